// Round 7
// baseline (4013.348 us; speedup 1.0000x reference)
//
#include <hip/hip_runtime.h>
#include <cstdio>
#include <cstdint>

// ---------- types / helpers ----------
typedef __attribute__((ext_vector_type(8))) short short8;   // 8 bf16 (4 VGPRs)
typedef __attribute__((ext_vector_type(4))) float f32x4;    // MFMA 16x16 acc

__device__ __forceinline__ f32x4 MFMA16(short8 a, short8 b, f32x4 c) {
  return __builtin_amdgcn_mfma_f32_16x16x32_bf16(a, b, c, 0, 0, 0);
}
__device__ __forceinline__ float bf2f(uint16_t u) {
  union { uint32_t u; float f; } v; v.u = ((uint32_t)u) << 16; return v.f;
}
__device__ __forceinline__ uint16_t f2bf(float f) {
  union { float f; uint32_t u; } v; v.f = f;
  uint32_t r = v.u + 0x7fffu + ((v.u >> 16) & 1u);  // RNE
  return (uint16_t)(r >> 16);
}
__device__ __forceinline__ float fsig(float x) { return 1.0f / (1.0f + __expf(-x)); }
__device__ __forceinline__ float ftanh_(float x) { return 2.0f / (1.0f + __expf(-2.0f * x)) - 1.0f; }

// Problem dims: B=128 S=256 L=16, EMB=256 HID=512, CEMB=64 CHID=128, NCLS=20
// word rows n = t*128 + b

// ---------- ws layout (bytes) ----------
#define OFF_CWI   0u
#define OFF_CWH   49152u
#define OFF_GWI   147456u
#define OFF_GWH   1327104u
#define OFF_CEMB  2899968u
#define OFF_CRZ   2916352u
#define OFF_CNI   2917376u
#define OFF_CNH   2917888u
#define OFF_WRZ   2918400u
#define OFF_WNI   2922496u
#define OFF_WNH   2924544u
#define OFF_CNT   2926592u      // 63488B sync region (15872 uints):
                                //  cluster c flags: [c*1024 + g*512 + gc*32], g in {A=0,B=1}
                                //  [10240]        topology rendezvous counter
                                //  [10272+x*32]   per-XCD claim counters (8)
#define OFF_CLSW  2990080u      // cls_W bf16 [20][512]
#define OFF_FEATS 3145728u      // bf16 [32768][384]
#define OFF_XW    28311552u     // bf16 [32768][1536]
#define OFF_H     128974848u    // bf16 [32768][512]  (= [256][128][512])
#define WS_NEEDED 162529280ull

// ---------- K0: weight convert + bias fuse + sync zero ----------
__global__ void k_prep(const float* __restrict__ cWi, const float* __restrict__ cWh,
                       const float* __restrict__ gWi, const float* __restrict__ gWh,
                       const float* __restrict__ cemb, const float* __restrict__ clsW,
                       const float* __restrict__ cbi, const float* __restrict__ cbh,
                       const float* __restrict__ gbi, const float* __restrict__ gbh,
                       uint16_t* o_cWi, uint16_t* o_cWh, uint16_t* o_gWi, uint16_t* o_gWh,
                       uint16_t* o_cemb, uint16_t* o_clsW,
                       float* o_crz, float* o_cni, float* o_cnh,
                       float* o_wrz, float* o_wni, float* o_wnh, unsigned* cnt)
{
  int g = blockIdx.x * 256 + threadIdx.x;
  int st = gridDim.x * 256;
  for (int i = g; i < 24576;  i += st) o_cWi[i] = f2bf(cWi[i]);
  for (int i = g; i < 49152;  i += st) o_cWh[i] = f2bf(cWh[i]);
  for (int i = g; i < 589824; i += st) o_gWi[i] = f2bf(gWi[i]);
  for (int i = g; i < 786432; i += st) o_gWh[i] = f2bf(gWh[i]);
  for (int i = g; i < 8192;   i += st) o_cemb[i] = f2bf(cemb[i]);
  for (int i = g; i < 10240;  i += st) o_clsW[i] = f2bf(clsW[i]);
  for (int i = g; i < 256;  i += st) o_crz[i] = cbi[i] + cbh[i];
  for (int i = g; i < 128;  i += st) { o_cni[i] = cbi[256 + i]; o_cnh[i] = cbh[256 + i]; }
  for (int i = g; i < 1024; i += st) o_wrz[i] = gbi[i] + gbh[i];
  for (int i = g; i < 512;  i += st) { o_wni[i] = gbi[1024 + i]; o_wnh[i] = gbh[1024 + i]; }
  for (int i = g; i < 15872; i += st) cnt[i] = 0u;   // whole sync region
}

// ---------- K2: word embedding gather -> feats[:, 0:256] ----------
__global__ void k_emb(const int* __restrict__ x, const float* __restrict__ embw,
                      uint16_t* __restrict__ feats)
{
  int n = blockIdx.x * 4 + (threadIdx.x >> 6);
  int lane = threadIdx.x & 63;
  int t = n >> 7, b = n & 127;
  int wid = x[b * 256 + t];
  float4 v = *(const float4*)(embw + (size_t)wid * 256 + lane * 4);
  uint16_t* dst = feats + (size_t)n * 384 + lane * 4;
  dst[0] = f2bf(v.x); dst[1] = f2bf(v.y); dst[2] = f2bf(v.z); dst[3] = f2bf(v.w);
}

// ---------- K1: char GRU (batch-parallel, MFMA) -> feats[:, 256:384] ----------
__global__ __launch_bounds__(256, 1) void k_char(
    const int* __restrict__ xch, const uint16_t* __restrict__ cembw,
    const uint16_t* __restrict__ cWi, const uint16_t* __restrict__ cWh,
    const float* __restrict__ crz, const float* __restrict__ cni,
    const float* __restrict__ cnh, uint16_t* __restrict__ feats)
{
  extern __shared__ char lds[];
  uint16_t* WhL = (uint16_t*)lds;                    // [384][136]
  int*      idsL = (int*)(lds + 104448);             // [64][17]
  uint16_t* hL  = (uint16_t*)(lds + 104448 + 4352);  // [64][136]
  const int tid = threadIdx.x;
  const int wbase = blockIdx.x * 64;

  for (int i = tid; i < 384 * 16; i += 256) {
    int row = i >> 4, ch = i & 15;
    *(uint4*)(WhL + row * 136 + ch * 8) = *(const uint4*)(cWh + row * 128 + ch * 8);
  }
  for (int i = tid; i < 64 * 16; i += 256) {
    int w0 = i >> 4, p = i & 15;
    idsL[w0 * 17 + p] = xch[(wbase + w0) * 16 + p];
  }
  for (int i = tid; i < 64 * 136 / 2; i += 256) ((unsigned*)hL)[i] = 0u;
  __syncthreads();

  const int wv = tid >> 6, lane = tid & 63;
  const int q = lane >> 4, c = lane & 15;
  float br_[8], bz_[8], bni_[8], bnh_[8];
#pragma unroll
  for (int jb = 0; jb < 8; ++jb) {
    int j = jb * 16 + c;
    br_[jb] = crz[j]; bz_[jb] = crz[128 + j]; bni_[jb] = cni[j]; bnh_[jb] = cnh[j];
  }
  const int lwA = wv * 16 + c;
  const int lwD = wv * 16 + q * 4;

  for (int t = 0; t < 16; ++t) {
    f32x4 aRZ[16], aXN[8], aGN[8];
#pragma unroll
    for (int i = 0; i < 16; ++i) aRZ[i] = (f32x4)0.0f;
#pragma unroll
    for (int i = 0; i < 8; ++i) { aXN[i] = (f32x4)0.0f; aGN[i] = (f32x4)0.0f; }

    int id = idsL[lwA * 17 + t];
    const uint16_t* cerow = cembw + id * 64;
    short8 Ae0 = *(const short8*)(cerow + q * 8);
    short8 Ae1 = *(const short8*)(cerow + 32 + q * 8);
#pragma unroll
    for (int tl = 0; tl < 24; ++tl) {
      const uint16_t* wr = cWi + (tl * 16 + c) * 64 + q * 8;
      short8 B0 = *(const short8*)(wr);
      short8 B1 = *(const short8*)(wr + 32);
      if (tl < 16) { aRZ[tl] = MFMA16(Ae0, B0, aRZ[tl]); aRZ[tl] = MFMA16(Ae1, B1, aRZ[tl]); }
      else { aXN[tl - 16] = MFMA16(Ae0, B0, aXN[tl - 16]); aXN[tl - 16] = MFMA16(Ae1, B1, aXN[tl - 16]); }
    }
    short8 Ah[4];
#pragma unroll
    for (int kt = 0; kt < 4; ++kt) Ah[kt] = *(const short8*)(hL + lwA * 136 + kt * 32 + q * 8);
#pragma unroll
    for (int tl = 0; tl < 24; ++tl) {
#pragma unroll
      for (int kt = 0; kt < 4; ++kt) {
        short8 Bw = *(const short8*)(WhL + (tl * 16 + c) * 136 + kt * 32 + q * 8);
        if (tl < 16) aRZ[tl] = MFMA16(Ah[kt], Bw, aRZ[tl]);
        else aGN[tl - 16] = MFMA16(Ah[kt], Bw, aGN[tl - 16]);
      }
    }
#pragma unroll
    for (int jb = 0; jb < 8; ++jb) {
      int j = jb * 16 + c;
#pragma unroll
      for (int rg = 0; rg < 4; ++rg) {
        float r = fsig(aRZ[jb][rg] + br_[jb]);
        float z = fsig(aRZ[8 + jb][rg] + bz_[jb]);
        float n = ftanh_(aXN[jb][rg] + bni_[jb] + r * (aGN[jb][rg] + bnh_[jb]));
        int hoff = (lwD + rg) * 136 + j;
        float hold = bf2f(hL[hoff]);
        hL[hoff] = f2bf((1.0f - z) * n + z * hold);
      }
    }
  }
  __syncthreads();
  for (int i = tid; i < 64 * 128; i += 256) {
    int w0 = i >> 7, col = i & 127;
    feats[(size_t)(wbase + w0) * 384 + 256 + col] = hL[w0 * 136 + col];
  }
}

// ---------- K3: xw = feats @ gru_Wi^T  (M=32768, N=1536, K=384) ----------
__global__ __launch_bounds__(256) void k_gemm_xw(
    const uint16_t* __restrict__ A, const uint16_t* __restrict__ Bm,
    uint16_t* __restrict__ C)
{
  __shared__ uint16_t AL[128 * 40];
  __shared__ uint16_t BL[128 * 40];
  const int tid = threadIdx.x;
  const int bm = blockIdx.x & 255, bn = blockIdx.x >> 8;
  const int m0 = bm * 128, n0 = bn * 128;
  const int wv = tid >> 6, lane = tid & 63, q = lane >> 4, c = lane & 15;
  const int vm = (wv >> 1) * 64, vn = (wv & 1) * 64;
  f32x4 acc[4][4];
#pragma unroll
  for (int mt = 0; mt < 4; ++mt)
#pragma unroll
    for (int nt = 0; nt < 4; ++nt) acc[mt][nt] = (f32x4)0.0f;

  for (int k0 = 0; k0 < 384; k0 += 32) {
    __syncthreads();
    for (int i2 = tid; i2 < 512; i2 += 256) {
      int row = i2 >> 2, cc = i2 & 3;
      *(uint4*)(AL + row * 40 + cc * 8) = *(const uint4*)(A + (size_t)(m0 + row) * 384 + k0 + cc * 8);
      *(uint4*)(BL + row * 40 + cc * 8) = *(const uint4*)(Bm + (size_t)(n0 + row) * 384 + k0 + cc * 8);
    }
    __syncthreads();
    short8 af[4], bfr[4];
#pragma unroll
    for (int mt = 0; mt < 4; ++mt) af[mt] = *(const short8*)(AL + (vm + mt * 16 + c) * 40 + q * 8);
#pragma unroll
    for (int nt = 0; nt < 4; ++nt) bfr[nt] = *(const short8*)(BL + (vn + nt * 16 + c) * 40 + q * 8);
#pragma unroll
    for (int mt = 0; mt < 4; ++mt)
#pragma unroll
      for (int nt = 0; nt < 4; ++nt) acc[mt][nt] = MFMA16(af[mt], bfr[nt], acc[mt][nt]);
  }
#pragma unroll
  for (int mt = 0; mt < 4; ++mt)
#pragma unroll
    for (int nt = 0; nt < 4; ++nt)
#pragma unroll
      for (int rg = 0; rg < 4; ++rg) {
        int m = m0 + vm + mt * 16 + q * 4 + rg;
        int n = n0 + vn + nt * 16 + c;
        C[(size_t)m * 1536 + n] = f2bf(acc[mt][nt][rg]);
      }
}

// ---------- K4: word GRU, persistent, 128 WGs x 64 thr, DUAL-GROUP PIPELINE ----
// Cluster = the 16 WGs on one XCD (topology-discovered). Cluster c computes
// batch groups A=c and B=(c+4)&7 redundantly (group g done by clusters g and
// (g+4)&7 — identical deterministic values, duplicate stores benign). All H
// exchange and flags are XCD-local. While group A's barrier propagates, the WG
// computes group B's step — barrier latency is hidden by real work.
// Flags: agent-scope atomics (R4-proven). Fallback (≠16/XCD): + threadfences.
__global__ __launch_bounds__(64, 1) void k_gru(
    const uint16_t* __restrict__ xw, const uint16_t* __restrict__ gWh,
    const float* __restrict__ wrz, const float* __restrict__ wni,
    const float* __restrict__ wnh, uint16_t* __restrict__ H,
    unsigned* __restrict__ cnt)
{
  extern __shared__ char lds[];
  uint16_t* WhL = (uint16_t*)lds;   // [96][520] = 99840 B
  const int tid = threadIdx.x;

  // ---- topology discovery ----
  unsigned xcd;
  asm volatile("s_getreg_b32 %0, hwreg(HW_REG_XCC_ID, 0, 4)" : "=s"(xcd));
  unsigned* rdv = cnt + 10240;
  int myslot = 0;
  if (tid == 0) {
    myslot = (int)__hip_atomic_fetch_add(cnt + 10272 + xcd * 32, 1u, __ATOMIC_RELAXED, __HIP_MEMORY_SCOPE_AGENT);
    __hip_atomic_fetch_add(rdv, 1u, __ATOMIC_RELEASE, __HIP_MEMORY_SCOPE_AGENT);
  }
  myslot = __shfl(myslot, 0);
  {
    int sp = 0;
    while (__hip_atomic_load(rdv, __ATOMIC_ACQUIRE, __HIP_MEMORY_SCOPE_AGENT) < 128u) {
      __builtin_amdgcn_s_sleep(1);
      if (++sp > 10000000) break;
    }
  }
  bool fastp = true;
#pragma unroll
  for (int x2 = 0; x2 < 8; ++x2) {
    unsigned v = __hip_atomic_load(cnt + 10272 + x2 * 32, __ATOMIC_RELAXED, __HIP_MEMORY_SCOPE_AGENT);
    if (v != 16u) fastp = false;
  }
  int cx, gc;
  if (fastp) { cx = (int)xcd; gc = myslot; }
  else       { cx = blockIdx.x >> 4; gc = blockIdx.x & 15; }
  const int gA = cx, gB = (cx + 4) & 7;
  const int m0A = gA * 16, m0B = gB * 16;
  const int j0 = gc * 32;
  unsigned* baseA = cnt + cx * 1024;
  unsigned* baseB = baseA + 512;
  unsigned* flagA = baseA + (gc << 5);
  unsigned* flagB = baseB + (gc << 5);

  for (int i = tid; i < 96 * 64; i += 64) {
    int row = i >> 6, ch = i & 63;
    int gr = (row < 32) ? (j0 + row) : (row < 64) ? (512 + j0 + row - 32) : (1024 + j0 + row - 64);
    *(uint4*)(WhL + row * 520 + ch * 8) = *(const uint4*)(gWh + (size_t)gr * 512 + ch * 8);
  }
  const int q = tid >> 4, c = tid & 15;
  const int j1 = j0 + c, j2 = j0 + 16 + c;
  const float br0 = wrz[j1], br1 = wrz[j2];
  const float bz0 = wrz[512 + j1], bz1 = wrz[512 + j2];
  const float bi0 = wni[j1], bi1 = wni[j2];
  const float bh0 = wnh[j1], bh1 = wnh[j2];
  __syncthreads();

  uint16_t pfA[4][6], pfB[4][6];
  float hA1[4] = {0,0,0,0}, hA2[4] = {0,0,0,0};
  float hB1[4] = {0,0,0,0}, hB2[4] = {0,0,0,0};

  auto prefetch_xw = [&](int tt, int m0, uint16_t (&pf)[4][6]) {
    const uint16_t* xwn = xw + (size_t)(tt * 128 + m0) * 1536;
#pragma unroll
    for (int rg = 0; rg < 4; ++rg) {
      const uint16_t* rowp = xwn + (q * 4 + rg) * 1536;
      pf[rg][0] = rowp[j1];        pf[rg][1] = rowp[j2];
      pf[rg][2] = rowp[512 + j1];  pf[rg][3] = rowp[512 + j2];
      pf[rg][4] = rowp[1024 + j1]; pf[rg][5] = rowp[1024 + j2];
    }
  };
  prefetch_xw(0, m0A, pfA);
  prefetch_xw(0, m0B, pfB);

  auto do_step = [&](int t, int m0, uint16_t (&pf)[4][6], float (&hold1)[4], float (&hold2)[4],
                     unsigned* myflag, unsigned* pollbase) {
    // poll: wait all 16 cluster WGs to have finished step t-1 of this group
    if (t > 0) {
      unsigned* watch = pollbase + ((tid & 15) << 5);
      int sp = 0;
      for (;;) {
        unsigned v = __hip_atomic_load(watch, __ATOMIC_RELAXED, __HIP_MEMORY_SCOPE_AGENT);
        if (__all((int)(v >= (unsigned)t))) break;
        if (++sp > 3000000) break;   // safety: terminate over hang
      }
      if (!fastp) __threadfence();
    }
    // H(t-1) fragment loads first (in-order vmcnt: before the HBM prefetch)
    short8 Ah[16];
    if (t > 0) {
      const uint16_t* hp = H + (size_t)((t - 1) * 128 + m0) * 512 + c * 512;
#pragma unroll
      for (int kt = 0; kt < 16; ++kt) Ah[kt] = *(const short8*)(hp + kt * 32 + q * 8);
    }
    // consume pf (VALU)
    f32x4 acc[6];
    float xn1[4], xn2[4];
#pragma unroll
    for (int rg = 0; rg < 4; ++rg) {
      acc[0][rg] = bf2f(pf[rg][0]); acc[1][rg] = bf2f(pf[rg][1]);
      acc[2][rg] = bf2f(pf[rg][2]); acc[3][rg] = bf2f(pf[rg][3]);
      acc[4][rg] = 0.0f; acc[5][rg] = 0.0f;
      xn1[rg] = bf2f(pf[rg][4]); xn2[rg] = bf2f(pf[rg][5]);
    }
    // prefetch xw(t+1): lands during MFMA/gates
    if (t < 255) prefetch_xw(t + 1, m0, pf);
    // MFMA: gh = h(t-1) @ Wh^T
    if (t > 0) {
#pragma unroll 4
      for (int kt = 0; kt < 16; ++kt) {
#pragma unroll
        for (int tl = 0; tl < 6; ++tl) {
          short8 b = *(const short8*)(WhL + (tl * 16 + c) * 520 + kt * 32 + q * 8);
          acc[tl] = MFMA16(Ah[kt], b, acc[tl]);
        }
      }
    }
    // gates + H store
    uint16_t* hcur = H + (size_t)(t * 128 + m0) * 512;
#pragma unroll
    for (int rg = 0; rg < 4; ++rg) {
      int m = q * 4 + rg;
      float r0 = fsig(acc[0][rg] + br0);
      float z0 = fsig(acc[2][rg] + bz0);
      float n0 = ftanh_(xn1[rg] + bi0 + r0 * (acc[4][rg] + bh0));
      float h0 = (1.0f - z0) * n0 + z0 * hold1[rg];
      hold1[rg] = h0;
      hcur[m * 512 + j1] = f2bf(h0);
      float r1 = fsig(acc[1][rg] + br1);
      float z1 = fsig(acc[3][rg] + bz1);
      float n1 = ftanh_(xn2[rg] + bi1 + r1 * (acc[5][rg] + bh1));
      float h1 = (1.0f - z1) * n1 + z1 * hold2[rg];
      hold2[rg] = h1;
      hcur[m * 512 + j2] = f2bf(h1);
    }
    // arrive: drain stores (and the already-landed prefetch), post flag
    if (t < 255) {
      asm volatile("s_waitcnt vmcnt(0)" ::: "memory");
      if (!fastp) __threadfence();
      if (tid == 0)
        __hip_atomic_store(myflag, (unsigned)(t + 1), __ATOMIC_RELAXED, __HIP_MEMORY_SCOPE_AGENT);
    }
  };

  for (int t = 0; t < 256; ++t) {
    do_step(t, m0A, pfA, hA1, hA2, flagA, baseA);
    do_step(t, m0B, pfB, hB1, hB2, flagB, baseB);
  }
}

// ---------- K5: classifier via MFMA: pred = H @ clsW^T + b ----------
__global__ __launch_bounds__(256) void k_cls(
    const uint16_t* __restrict__ H, const uint16_t* __restrict__ Wb,
    const float* __restrict__ bb, float* __restrict__ out)
{
  __shared__ uint16_t WsL[32 * 520];
  const int tid = threadIdx.x;
  for (int i = tid; i < 2048; i += 256) {
    int row = i >> 6, col = (i & 63) * 8;
    uint4 v = (row < 20) ? *(const uint4*)(Wb + row * 512 + col) : make_uint4(0u, 0u, 0u, 0u);
    *(uint4*)(WsL + row * 520 + col) = v;
  }
  __syncthreads();
  const int wv = tid >> 6, lane = tid & 63, q = lane >> 4, c = lane & 15;
  const int rowbase = blockIdx.x * 64 + wv * 16;
  f32x4 a0 = (f32x4)0.0f, a1 = (f32x4)0.0f;
  const uint16_t* hp = H + (size_t)(rowbase + c) * 512 + q * 8;
#pragma unroll
  for (int kt = 0; kt < 16; ++kt) {
    short8 a = *(const short8*)(hp + kt * 32);
    short8 b0 = *(const short8*)(WsL + c * 520 + kt * 32 + q * 8);
    short8 b1 = *(const short8*)(WsL + (16 + c) * 520 + kt * 32 + q * 8);
    a0 = MFMA16(a, b0, a0);
    a1 = MFMA16(a, b1, a1);
  }
  const float bias0 = bb[c];
  const float bias1 = (c < 4) ? bb[16 + c] : 0.0f;
#pragma unroll
  for (int rg = 0; rg < 4; ++rg) {
    int row = rowbase + q * 4 + rg;
    int t = row >> 7, b = row & 127;
    float* op = out + ((size_t)b * 256 + t) * 20;
    op[c] = a0[rg] + bias0;
    if (c < 4) op[16 + c] = a1[rg] + bias1;
  }
}

// ---------- launch ----------
extern "C" void kernel_launch(void* const* d_in, const int* in_sizes, int n_in,
                              void* d_out, int out_size, void* d_ws, size_t ws_size,
                              hipStream_t stream) {
  (void)in_sizes; (void)n_in; (void)out_size;
  const int*   x     = (const int*)d_in[0];
  const int*   xch   = (const int*)d_in[1];
  const float* embw  = (const float*)d_in[2];
  const float* cembw = (const float*)d_in[3];
  const float* cWi   = (const float*)d_in[4];
  const float* cWh   = (const float*)d_in[5];
  const float* cbi   = (const float*)d_in[6];
  const float* cbh   = (const float*)d_in[7];
  const float* gWi   = (const float*)d_in[8];
  const float* gWh   = (const float*)d_in[9];
  const float* gbi   = (const float*)d_in[10];
  const float* gbh   = (const float*)d_in[11];
  const float* clsW  = (const float*)d_in[12];
  const float* clsb  = (const float*)d_in[13];
  float* out = (float*)d_out;
  char* w = (char*)d_ws;

  if (ws_size < WS_NEEDED) { fprintf(stderr, "ws too small: %zu < %llu\n", ws_size, WS_NEEDED); return; }

  uint16_t* o_cWi  = (uint16_t*)(w + OFF_CWI);
  uint16_t* o_cWh  = (uint16_t*)(w + OFF_CWH);
  uint16_t* o_gWi  = (uint16_t*)(w + OFF_GWI);
  uint16_t* o_gWh  = (uint16_t*)(w + OFF_GWH);
  uint16_t* o_cemb = (uint16_t*)(w + OFF_CEMB);
  uint16_t* o_clsW = (uint16_t*)(w + OFF_CLSW);
  float* crz = (float*)(w + OFF_CRZ);
  float* cni = (float*)(w + OFF_CNI);
  float* cnh = (float*)(w + OFF_CNH);
  float* wrz = (float*)(w + OFF_WRZ);
  float* wni = (float*)(w + OFF_WNI);
  float* wnh = (float*)(w + OFF_WNH);
  unsigned* cnt = (unsigned*)(w + OFF_CNT);
  uint16_t* feats = (uint16_t*)(w + OFF_FEATS);
  uint16_t* xwb   = (uint16_t*)(w + OFF_XW);
  uint16_t* Hb    = (uint16_t*)(w + OFF_H);

  (void)hipFuncSetAttribute((const void*)k_char, hipFuncAttributeMaxDynamicSharedMemorySize, 126208);
  (void)hipFuncSetAttribute((const void*)k_gru,  hipFuncAttributeMaxDynamicSharedMemorySize, 99840);

  k_prep<<<512, 256, 0, stream>>>(cWi, cWh, gWi, gWh, cembw, clsW, cbi, cbh, gbi, gbh,
                                  o_cWi, o_cWh, o_gWi, o_gWh, o_cemb, o_clsW,
                                  crz, cni, cnh, wrz, wni, wnh, cnt);
  k_emb<<<8192, 256, 0, stream>>>(x, embw, feats);
  k_char<<<512, 256, 126208, stream>>>(xch, o_cemb, o_cWi, o_cWh, crz, cni, cnh, feats);
  k_gemm_xw<<<3072, 256, 0, stream>>>(feats, o_gWi, xwb);
  k_gru<<<128, 64, 99840, stream>>>(xwb, o_gWh, wrz, wni, wnh, Hb, cnt);
  k_cls<<<512, 256, 0, stream>>>(Hb, o_clsW, clsb, out);
}

// Round 8
// 1729.545 us; speedup vs baseline: 2.3205x; 2.3205x over previous
//
#include <hip/hip_runtime.h>
#include <cstdio>
#include <cstdint>

// ---------- types / helpers ----------
typedef __attribute__((ext_vector_type(8))) short short8;   // 8 bf16 (4 VGPRs)
typedef __attribute__((ext_vector_type(4))) float f32x4;    // MFMA 16x16 acc

__device__ __forceinline__ f32x4 MFMA16(short8 a, short8 b, f32x4 c) {
  return __builtin_amdgcn_mfma_f32_16x16x32_bf16(a, b, c, 0, 0, 0);
}
__device__ __forceinline__ float bf2f(uint16_t u) {
  union { uint32_t u; float f; } v; v.u = ((uint32_t)u) << 16; return v.f;
}
__device__ __forceinline__ uint16_t f2bf(float f) {
  union { float f; uint32_t u; } v; v.f = f;
  uint32_t r = v.u + 0x7fffu + ((v.u >> 16) & 1u);  // RNE
  return (uint16_t)(r >> 16);
}
__device__ __forceinline__ float fsig(float x) { return 1.0f / (1.0f + __expf(-x)); }
__device__ __forceinline__ float ftanh_(float x) { return 2.0f / (1.0f + __expf(-2.0f * x)) - 1.0f; }

// Problem dims: B=128 S=256 L=16, EMB=256 HID=512, CEMB=64 CHID=128, NCLS=20
// word rows n = t*128 + b

// ---------- ws layout (bytes) ----------
#define OFF_CWI   0u
#define OFF_CWH   49152u
#define OFF_GWI   147456u
#define OFF_GWH   1327104u
#define OFF_CEMB  2899968u
#define OFF_CRZ   2916352u
#define OFF_CNI   2917376u
#define OFF_CNH   2917888u
#define OFF_WRZ   2918400u
#define OFF_WNI   2922496u
#define OFF_WNH   2924544u
#define OFF_CNT   2926592u      // 63488B sync region (15872 uints):
                                //  [10240]         topology rendezvous counter
                                //  [10272+x*32]    per-XCD claim counters (8)
                                //  [10528+gb*128]  step counters (8, 512B apart)
#define OFF_CLSW  2990080u      // cls_W bf16 [20][512]
#define OFF_FEATS 3145728u      // bf16 [32768][384]
#define OFF_XW    28311552u     // bf16 [32768][1536]
#define OFF_H     128974848u    // bf16 [32768][512]  (= [256][128][512])
#define WS_NEEDED 162529280ull

// ---------- K0: weight convert + bias fuse + sync zero ----------
__global__ void k_prep(const float* __restrict__ cWi, const float* __restrict__ cWh,
                       const float* __restrict__ gWi, const float* __restrict__ gWh,
                       const float* __restrict__ cemb, const float* __restrict__ clsW,
                       const float* __restrict__ cbi, const float* __restrict__ cbh,
                       const float* __restrict__ gbi, const float* __restrict__ gbh,
                       uint16_t* o_cWi, uint16_t* o_cWh, uint16_t* o_gWi, uint16_t* o_gWh,
                       uint16_t* o_cemb, uint16_t* o_clsW,
                       float* o_crz, float* o_cni, float* o_cnh,
                       float* o_wrz, float* o_wni, float* o_wnh, unsigned* cnt)
{
  int g = blockIdx.x * 256 + threadIdx.x;
  int st = gridDim.x * 256;
  for (int i = g; i < 24576;  i += st) o_cWi[i] = f2bf(cWi[i]);
  for (int i = g; i < 49152;  i += st) o_cWh[i] = f2bf(cWh[i]);
  for (int i = g; i < 589824; i += st) o_gWi[i] = f2bf(gWi[i]);
  for (int i = g; i < 786432; i += st) o_gWh[i] = f2bf(gWh[i]);
  for (int i = g; i < 8192;   i += st) o_cemb[i] = f2bf(cemb[i]);
  for (int i = g; i < 10240;  i += st) o_clsW[i] = f2bf(clsW[i]);
  for (int i = g; i < 256;  i += st) o_crz[i] = cbi[i] + cbh[i];
  for (int i = g; i < 128;  i += st) { o_cni[i] = cbi[256 + i]; o_cnh[i] = cbh[256 + i]; }
  for (int i = g; i < 1024; i += st) o_wrz[i] = gbi[i] + gbh[i];
  for (int i = g; i < 512;  i += st) { o_wni[i] = gbi[1024 + i]; o_wnh[i] = gbh[1024 + i]; }
  for (int i = g; i < 15872; i += st) cnt[i] = 0u;   // whole sync region
}

// ---------- K2: word embedding gather -> feats[:, 0:256] ----------
__global__ void k_emb(const int* __restrict__ x, const float* __restrict__ embw,
                      uint16_t* __restrict__ feats)
{
  int n = blockIdx.x * 4 + (threadIdx.x >> 6);
  int lane = threadIdx.x & 63;
  int t = n >> 7, b = n & 127;
  int wid = x[b * 256 + t];
  float4 v = *(const float4*)(embw + (size_t)wid * 256 + lane * 4);
  uint16_t* dst = feats + (size_t)n * 384 + lane * 4;
  dst[0] = f2bf(v.x); dst[1] = f2bf(v.y); dst[2] = f2bf(v.z); dst[3] = f2bf(v.w);
}

// ---------- K1: char GRU (batch-parallel, MFMA) -> feats[:, 256:384] ----------
__global__ __launch_bounds__(256, 1) void k_char(
    const int* __restrict__ xch, const uint16_t* __restrict__ cembw,
    const uint16_t* __restrict__ cWi, const uint16_t* __restrict__ cWh,
    const float* __restrict__ crz, const float* __restrict__ cni,
    const float* __restrict__ cnh, uint16_t* __restrict__ feats)
{
  extern __shared__ char lds[];
  uint16_t* WhL = (uint16_t*)lds;                    // [384][136]
  int*      idsL = (int*)(lds + 104448);             // [64][17]
  uint16_t* hL  = (uint16_t*)(lds + 104448 + 4352);  // [64][136]
  const int tid = threadIdx.x;
  const int wbase = blockIdx.x * 64;

  for (int i = tid; i < 384 * 16; i += 256) {
    int row = i >> 4, ch = i & 15;
    *(uint4*)(WhL + row * 136 + ch * 8) = *(const uint4*)(cWh + row * 128 + ch * 8);
  }
  for (int i = tid; i < 64 * 16; i += 256) {
    int w0 = i >> 4, p = i & 15;
    idsL[w0 * 17 + p] = xch[(wbase + w0) * 16 + p];
  }
  for (int i = tid; i < 64 * 136 / 2; i += 256) ((unsigned*)hL)[i] = 0u;
  __syncthreads();

  const int wv = tid >> 6, lane = tid & 63;
  const int q = lane >> 4, c = lane & 15;
  float br_[8], bz_[8], bni_[8], bnh_[8];
#pragma unroll
  for (int jb = 0; jb < 8; ++jb) {
    int j = jb * 16 + c;
    br_[jb] = crz[j]; bz_[jb] = crz[128 + j]; bni_[jb] = cni[j]; bnh_[jb] = cnh[j];
  }
  const int lwA = wv * 16 + c;
  const int lwD = wv * 16 + q * 4;

  for (int t = 0; t < 16; ++t) {
    f32x4 aRZ[16], aXN[8], aGN[8];
#pragma unroll
    for (int i = 0; i < 16; ++i) aRZ[i] = (f32x4)0.0f;
#pragma unroll
    for (int i = 0; i < 8; ++i) { aXN[i] = (f32x4)0.0f; aGN[i] = (f32x4)0.0f; }

    int id = idsL[lwA * 17 + t];
    const uint16_t* cerow = cembw + id * 64;
    short8 Ae0 = *(const short8*)(cerow + q * 8);
    short8 Ae1 = *(const short8*)(cerow + 32 + q * 8);
#pragma unroll
    for (int tl = 0; tl < 24; ++tl) {
      const uint16_t* wr = cWi + (tl * 16 + c) * 64 + q * 8;
      short8 B0 = *(const short8*)(wr);
      short8 B1 = *(const short8*)(wr + 32);
      if (tl < 16) { aRZ[tl] = MFMA16(Ae0, B0, aRZ[tl]); aRZ[tl] = MFMA16(Ae1, B1, aRZ[tl]); }
      else { aXN[tl - 16] = MFMA16(Ae0, B0, aXN[tl - 16]); aXN[tl - 16] = MFMA16(Ae1, B1, aXN[tl - 16]); }
    }
    short8 Ah[4];
#pragma unroll
    for (int kt = 0; kt < 4; ++kt) Ah[kt] = *(const short8*)(hL + lwA * 136 + kt * 32 + q * 8);
#pragma unroll
    for (int tl = 0; tl < 24; ++tl) {
#pragma unroll
      for (int kt = 0; kt < 4; ++kt) {
        short8 Bw = *(const short8*)(WhL + (tl * 16 + c) * 136 + kt * 32 + q * 8);
        if (tl < 16) aRZ[tl] = MFMA16(Ah[kt], Bw, aRZ[tl]);
        else aGN[tl - 16] = MFMA16(Ah[kt], Bw, aGN[tl - 16]);
      }
    }
#pragma unroll
    for (int jb = 0; jb < 8; ++jb) {
      int j = jb * 16 + c;
#pragma unroll
      for (int rg = 0; rg < 4; ++rg) {
        float r = fsig(aRZ[jb][rg] + br_[jb]);
        float z = fsig(aRZ[8 + jb][rg] + bz_[jb]);
        float n = ftanh_(aXN[jb][rg] + bni_[jb] + r * (aGN[jb][rg] + bnh_[jb]));
        int hoff = (lwD + rg) * 136 + j;
        float hold = bf2f(hL[hoff]);
        hL[hoff] = f2bf((1.0f - z) * n + z * hold);
      }
    }
  }
  __syncthreads();
  for (int i = tid; i < 64 * 128; i += 256) {
    int w0 = i >> 7, col = i & 127;
    feats[(size_t)(wbase + w0) * 384 + 256 + col] = hL[w0 * 136 + col];
  }
}

// ---------- K3: xw = feats @ gru_Wi^T  (M=32768, N=1536, K=384) ----------
__global__ __launch_bounds__(256) void k_gemm_xw(
    const uint16_t* __restrict__ A, const uint16_t* __restrict__ Bm,
    uint16_t* __restrict__ C)
{
  __shared__ uint16_t AL[128 * 40];
  __shared__ uint16_t BL[128 * 40];
  const int tid = threadIdx.x;
  const int bm = blockIdx.x & 255, bn = blockIdx.x >> 8;
  const int m0 = bm * 128, n0 = bn * 128;
  const int wv = tid >> 6, lane = tid & 63, q = lane >> 4, c = lane & 15;
  const int vm = (wv >> 1) * 64, vn = (wv & 1) * 64;
  f32x4 acc[4][4];
#pragma unroll
  for (int mt = 0; mt < 4; ++mt)
#pragma unroll
    for (int nt = 0; nt < 4; ++nt) acc[mt][nt] = (f32x4)0.0f;

  for (int k0 = 0; k0 < 384; k0 += 32) {
    __syncthreads();
    for (int i2 = tid; i2 < 512; i2 += 256) {
      int row = i2 >> 2, cc = i2 & 3;
      *(uint4*)(AL + row * 40 + cc * 8) = *(const uint4*)(A + (size_t)(m0 + row) * 384 + k0 + cc * 8);
      *(uint4*)(BL + row * 40 + cc * 8) = *(const uint4*)(Bm + (size_t)(n0 + row) * 384 + k0 + cc * 8);
    }
    __syncthreads();
    short8 af[4], bfr[4];
#pragma unroll
    for (int mt = 0; mt < 4; ++mt) af[mt] = *(const short8*)(AL + (vm + mt * 16 + c) * 40 + q * 8);
#pragma unroll
    for (int nt = 0; nt < 4; ++nt) bfr[nt] = *(const short8*)(BL + (vn + nt * 16 + c) * 40 + q * 8);
#pragma unroll
    for (int mt = 0; mt < 4; ++mt)
#pragma unroll
      for (int nt = 0; nt < 4; ++nt) acc[mt][nt] = MFMA16(af[mt], bfr[nt], acc[mt][nt]);
  }
#pragma unroll
  for (int mt = 0; mt < 4; ++mt)
#pragma unroll
    for (int nt = 0; nt < 4; ++nt)
#pragma unroll
      for (int rg = 0; rg < 4; ++rg) {
        int m = m0 + vm + mt * 16 + q * 4 + rg;
        int n = n0 + vn + nt * 16 + c;
        C[(size_t)m * 1536 + n] = f2bf(acc[mt][nt][rg]);
      }
}

// ---------- K4: word GRU, persistent, 128 WGs x 64 thr ----------
// R4 structure (single group per WG, XCD-local groups of 16). Barrier redesigned
// for MINIMUM fabric pressure (congestion model from R7 post-mortem):
//   arrive: drain 8 H-stores (vmcnt 0), then ONE atomic add per WG to the group
//           counter (agent scope — coherence point).
//   detect: ONE lane (tid==0) polls the single counter with s_sleep backoff;
//           other 63 lanes wait at exec-mask reconvergence. ~300x less poll
//           traffic than R4's 64-lane no-backoff spin.
//   prefetch: issued AFTER the arrive so the flag never queues behind HBM loads;
//           overlaps the poll sleep.
// Fallback (non-XCD-local placement): same + threadfences.
__global__ __launch_bounds__(64, 1) void k_gru(
    const uint16_t* __restrict__ xw, const uint16_t* __restrict__ gWh,
    const float* __restrict__ wrz, const float* __restrict__ wni,
    const float* __restrict__ wnh, uint16_t* __restrict__ H,
    unsigned* __restrict__ cnt)
{
  extern __shared__ char lds[];
  uint16_t* WhL = (uint16_t*)lds;   // [96][520] = 99840 B
  const int tid = threadIdx.x;

  // ---- topology discovery ----
  unsigned xcd;
  asm volatile("s_getreg_b32 %0, hwreg(HW_REG_XCC_ID, 0, 4)" : "=s"(xcd));
  unsigned* rdv = cnt + 10240;
  int myslot = 0;
  if (tid == 0) {
    myslot = (int)__hip_atomic_fetch_add(cnt + 10272 + xcd * 32, 1u, __ATOMIC_RELAXED, __HIP_MEMORY_SCOPE_AGENT);
    __hip_atomic_fetch_add(rdv, 1u, __ATOMIC_RELEASE, __HIP_MEMORY_SCOPE_AGENT);
  }
  myslot = __shfl(myslot, 0);
  {
    int sp = 0;
    while (__hip_atomic_load(rdv, __ATOMIC_ACQUIRE, __HIP_MEMORY_SCOPE_AGENT) < 128u) {
      __builtin_amdgcn_s_sleep(1);
      if (++sp > 10000000) break;
    }
  }
  unsigned G = 0, base = 0;
#pragma unroll
  for (int x2 = 0; x2 < 8; ++x2) {
    unsigned v = __hip_atomic_load(cnt + 10272 + x2 * 32, __ATOMIC_RELAXED, __HIP_MEMORY_SCOPE_AGENT) >> 4;
    if ((unsigned)x2 < xcd) base += v;
    G += v;
  }
  bool fastp; int gb, gc;
  if (G == 8u) { fastp = true; gb = (int)(base + ((unsigned)myslot >> 4)); gc = myslot & 15; }
  else         { fastp = false; gb = blockIdx.x & 7; gc = blockIdx.x >> 3; }

  const int m0 = gb * 16, j0 = gc * 32;
  unsigned* myCnt = cnt + 10528 + (gb << 7);   // group step counter, 512B apart

  for (int i = tid; i < 96 * 64; i += 64) {
    int row = i >> 6, ch = i & 63;
    int gr = (row < 32) ? (j0 + row) : (row < 64) ? (512 + j0 + row - 32) : (1024 + j0 + row - 64);
    *(uint4*)(WhL + row * 520 + ch * 8) = *(const uint4*)(gWh + (size_t)gr * 512 + ch * 8);
  }
  const int q = tid >> 4, c = tid & 15;
  const int j1 = j0 + c, j2 = j0 + 16 + c;
  const float br0 = wrz[j1], br1 = wrz[j2];
  const float bz0 = wrz[512 + j1], bz1 = wrz[512 + j2];
  const float bi0 = wni[j1], bi1 = wni[j2];
  const float bh0 = wnh[j1], bh1 = wnh[j2];
  __syncthreads();

  uint16_t pf[4][6];
  auto prefetch_xw = [&](int tt) {
    const uint16_t* xwn = xw + (size_t)(tt * 128 + m0) * 1536;
#pragma unroll
    for (int rg = 0; rg < 4; ++rg) {
      const uint16_t* rowp = xwn + (q * 4 + rg) * 1536;
      pf[rg][0] = rowp[j1];        pf[rg][1] = rowp[j2];
      pf[rg][2] = rowp[512 + j1];  pf[rg][3] = rowp[512 + j2];
      pf[rg][4] = rowp[1024 + j1]; pf[rg][5] = rowp[1024 + j2];
    }
  };
  prefetch_xw(0);
  float hold1[4] = {0.f, 0.f, 0.f, 0.f}, hold2[4] = {0.f, 0.f, 0.f, 0.f};

  for (int t = 0; t < 256; ++t) {
    // (1) wait: group counter reaches 16*t (single-lane poll, backoff)
    if (t > 0) {
      const unsigned target = (unsigned)t * 16u;
      if (tid == 0) {
        int sp = 0;
        while (__hip_atomic_load(myCnt, __ATOMIC_RELAXED, __HIP_MEMORY_SCOPE_AGENT) < target) {
          __builtin_amdgcn_s_sleep(2);
          if (++sp > 100000) break;   // safety: terminate over hang
        }
      }
      if (!fastp) __threadfence();
      asm volatile("" ::: "memory");
    }
    // (2) H(t-1) fragment loads (issue first; nothing else outstanding)
    short8 Ah[16];
    if (t > 0) {
      const uint16_t* hp = H + (size_t)((t - 1) * 128 + m0) * 512 + c * 512;
#pragma unroll
      for (int kt = 0; kt < 16; ++kt) Ah[kt] = *(const short8*)(hp + kt * 32 + q * 8);
    }
    // (3) consume pf (VALU, overlaps H loads)
    f32x4 acc[6];
    float xn1[4], xn2[4];
#pragma unroll
    for (int rg = 0; rg < 4; ++rg) {
      acc[0][rg] = bf2f(pf[rg][0]); acc[1][rg] = bf2f(pf[rg][1]);
      acc[2][rg] = bf2f(pf[rg][2]); acc[3][rg] = bf2f(pf[rg][3]);
      acc[4][rg] = 0.0f; acc[5][rg] = 0.0f;
      xn1[rg] = bf2f(pf[rg][4]); xn2[rg] = bf2f(pf[rg][5]);
    }
    // (4) MFMA: gh = h(t-1) @ Wh^T
    if (t > 0) {
#pragma unroll 4
      for (int kt = 0; kt < 16; ++kt) {
#pragma unroll
        for (int tl = 0; tl < 6; ++tl) {
          short8 b = *(const short8*)(WhL + (tl * 16 + c) * 520 + kt * 32 + q * 8);
          acc[tl] = MFMA16(Ah[kt], b, acc[tl]);
        }
      }
    }
    // (5) gates + H store
    uint16_t* hcur = H + (size_t)(t * 128 + m0) * 512;
#pragma unroll
    for (int rg = 0; rg < 4; ++rg) {
      int m = q * 4 + rg;
      float r0 = fsig(acc[0][rg] + br0);
      float z0 = fsig(acc[2][rg] + bz0);
      float n0 = ftanh_(xn1[rg] + bi0 + r0 * (acc[4][rg] + bh0));
      float h0 = (1.0f - z0) * n0 + z0 * hold1[rg];
      hold1[rg] = h0;
      hcur[m * 512 + j1] = f2bf(h0);
      float r1 = fsig(acc[1][rg] + br1);
      float z1 = fsig(acc[3][rg] + bz1);
      float n1 = ftanh_(xn2[rg] + bi1 + r1 * (acc[5][rg] + bh1));
      float h1 = (1.0f - z1) * n1 + z1 * hold2[rg];
      hold2[rg] = h1;
      hcur[m * 512 + j2] = f2bf(h1);
    }
    if (t == 255) break;
    // (6) arrive: drain the 8 H-stores only, then one atomic add per WG
    asm volatile("s_waitcnt vmcnt(0)" ::: "memory");
    if (!fastp) __threadfence();
    if (tid == 0)
      __hip_atomic_fetch_add(myCnt, 1u, __ATOMIC_RELAXED, __HIP_MEMORY_SCOPE_AGENT);
    // (7) prefetch xw(t+1): overlaps the next poll's sleep
    prefetch_xw(t + 1);
  }
}

// ---------- K5: classifier via MFMA: pred = H @ clsW^T + b ----------
__global__ __launch_bounds__(256) void k_cls(
    const uint16_t* __restrict__ H, const uint16_t* __restrict__ Wb,
    const float* __restrict__ bb, float* __restrict__ out)
{
  __shared__ uint16_t WsL[32 * 520];
  const int tid = threadIdx.x;
  for (int i = tid; i < 2048; i += 256) {
    int row = i >> 6, col = (i & 63) * 8;
    uint4 v = (row < 20) ? *(const uint4*)(Wb + row * 512 + col) : make_uint4(0u, 0u, 0u, 0u);
    *(uint4*)(WsL + row * 520 + col) = v;
  }
  __syncthreads();
  const int wv = tid >> 6, lane = tid & 63, q = lane >> 4, c = lane & 15;
  const int rowbase = blockIdx.x * 64 + wv * 16;
  f32x4 a0 = (f32x4)0.0f, a1 = (f32x4)0.0f;
  const uint16_t* hp = H + (size_t)(rowbase + c) * 512 + q * 8;
#pragma unroll
  for (int kt = 0; kt < 16; ++kt) {
    short8 a = *(const short8*)(hp + kt * 32);
    short8 b0 = *(const short8*)(WsL + c * 520 + kt * 32 + q * 8);
    short8 b1 = *(const short8*)(WsL + (16 + c) * 520 + kt * 32 + q * 8);
    a0 = MFMA16(a, b0, a0);
    a1 = MFMA16(a, b1, a1);
  }
  const float bias0 = bb[c];
  const float bias1 = (c < 4) ? bb[16 + c] : 0.0f;
#pragma unroll
  for (int rg = 0; rg < 4; ++rg) {
    int row = rowbase + q * 4 + rg;
    int t = row >> 7, b = row & 127;
    float* op = out + ((size_t)b * 256 + t) * 20;
    op[c] = a0[rg] + bias0;
    if (c < 4) op[16 + c] = a1[rg] + bias1;
  }
}

// ---------- launch ----------
extern "C" void kernel_launch(void* const* d_in, const int* in_sizes, int n_in,
                              void* d_out, int out_size, void* d_ws, size_t ws_size,
                              hipStream_t stream) {
  (void)in_sizes; (void)n_in; (void)out_size;
  const int*   x     = (const int*)d_in[0];
  const int*   xch   = (const int*)d_in[1];
  const float* embw  = (const float*)d_in[2];
  const float* cembw = (const float*)d_in[3];
  const float* cWi   = (const float*)d_in[4];
  const float* cWh   = (const float*)d_in[5];
  const float* cbi   = (const float*)d_in[6];
  const float* cbh   = (const float*)d_in[7];
  const float* gWi   = (const float*)d_in[8];
  const float* gWh   = (const float*)d_in[9];
  const float* gbi   = (const float*)d_in[10];
  const float* gbh   = (const float*)d_in[11];
  const float* clsW  = (const float*)d_in[12];
  const float* clsb  = (const float*)d_in[13];
  float* out = (float*)d_out;
  char* w = (char*)d_ws;

  if (ws_size < WS_NEEDED) { fprintf(stderr, "ws too small: %zu < %llu\n", ws_size, WS_NEEDED); return; }

  uint16_t* o_cWi  = (uint16_t*)(w + OFF_CWI);
  uint16_t* o_cWh  = (uint16_t*)(w + OFF_CWH);
  uint16_t* o_gWi  = (uint16_t*)(w + OFF_GWI);
  uint16_t* o_gWh  = (uint16_t*)(w + OFF_GWH);
  uint16_t* o_cemb = (uint16_t*)(w + OFF_CEMB);
  uint16_t* o_clsW = (uint16_t*)(w + OFF_CLSW);
  float* crz = (float*)(w + OFF_CRZ);
  float* cni = (float*)(w + OFF_CNI);
  float* cnh = (float*)(w + OFF_CNH);
  float* wrz = (float*)(w + OFF_WRZ);
  float* wni = (float*)(w + OFF_WNI);
  float* wnh = (float*)(w + OFF_WNH);
  unsigned* cnt = (unsigned*)(w + OFF_CNT);
  uint16_t* feats = (uint16_t*)(w + OFF_FEATS);
  uint16_t* xwb   = (uint16_t*)(w + OFF_XW);
  uint16_t* Hb    = (uint16_t*)(w + OFF_H);

  (void)hipFuncSetAttribute((const void*)k_char, hipFuncAttributeMaxDynamicSharedMemorySize, 126208);
  (void)hipFuncSetAttribute((const void*)k_gru,  hipFuncAttributeMaxDynamicSharedMemorySize, 99840);

  k_prep<<<512, 256, 0, stream>>>(cWi, cWh, gWi, gWh, cembw, clsW, cbi, cbh, gbi, gbh,
                                  o_cWi, o_cWh, o_gWi, o_gWh, o_cemb, o_clsW,
                                  crz, cni, cnh, wrz, wni, wnh, cnt);
  k_emb<<<8192, 256, 0, stream>>>(x, embw, feats);
  k_char<<<512, 256, 126208, stream>>>(xch, o_cemb, o_cWi, o_cWh, crz, cni, cnh, feats);
  k_gemm_xw<<<3072, 256, 0, stream>>>(feats, o_gWi, xwb);
  k_gru<<<128, 64, 99840, stream>>>(xwb, o_gWh, wrz, wni, wnh, Hb, cnt);
  k_cls<<<512, 256, 0, stream>>>(Hb, o_clsW, clsb, out);
}